// Round 16
// baseline (241.924 us; speedup 1.0000x reference)
//
#include <hip/hip_runtime.h>
#include <stdint.h>

#define DEV static __device__ __forceinline__

typedef __bf16 bf16_t;
typedef bf16_t bf16x8 __attribute__((ext_vector_type(8)));
typedef bf16_t bf16x4 __attribute__((ext_vector_type(4)));
typedef float f32x4 __attribute__((ext_vector_type(4)));

static constexpr int Bc = 4, Sc = 2048, Dc = 1024, Hc = 16, DKc = 64;
static constexpr int Mrows = Bc * Sc; // 8192

DEV unsigned short f2bf(float f) {
  unsigned int u = __float_as_uint(f);
  u += 0x7fffu + ((u >> 16) & 1u);
  return (unsigned short)(u >> 16);
}

DEV float fexp2(float x) {
#if __has_builtin(__builtin_amdgcn_exp2f)
  return __builtin_amdgcn_exp2f(x); // single v_exp_f32
#else
  return exp2f(x);
#endif
}

// 16x16x16 bf16 MFMA (K=16): A-frag k-granularity = lhi*4 -- matches the
// swapped-QK^T D-layout exactly, so P feeds PV straight from registers.
#if __has_builtin(__builtin_amdgcn_mfma_f32_16x16x16_bf16)
DEV f32x4 mfma16(bf16x4 a, bf16x4 b, f32x4 c) {
  return __builtin_amdgcn_mfma_f32_16x16x16_bf16(a, b, c, 0, 0, 0);
}
#elif __has_builtin(__builtin_amdgcn_mfma_f32_16x16x16bf16_1k)
typedef short s16x4 __attribute__((ext_vector_type(4)));
DEV f32x4 mfma16(bf16x4 a, bf16x4 b, f32x4 c) {
  union U { bf16x4 h; s16x4 s; };
  U ua, ub; ua.h = a; ub.h = b;
  return __builtin_amdgcn_mfma_f32_16x16x16bf16_1k(ua.s, ub.s, c, 0, 0, 0);
}
#else
DEV f32x4 mfma16(bf16x4 a, bf16x4 b, f32x4 c) {
  asm("v_mfma_f32_16x16x16_bf16 %0, %1, %2, %0" : "+v"(c) : "v"(a), "v"(b));
  return c;
}
#endif

DEV void gload_lds16(const void* g, void* l) {
  __builtin_amdgcn_global_load_lds(
      (const __attribute__((address_space(1))) void*)g,
      (__attribute__((address_space(3))) void*)l, 16, 0, 0);
}

// 8 fp32 -> bf16x8 (RTNE; compiler emits v_cvt_pk_bf16_f32 pairs)
DEV bf16x8 cvt8(float4 a, float4 b) {
  bf16x8 r;
  r[0] = (bf16_t)a.x; r[1] = (bf16_t)a.y; r[2] = (bf16_t)a.z; r[3] = (bf16_t)a.w;
  r[4] = (bf16_t)b.x; r[5] = (bf16_t)b.y; r[6] = (bf16_t)b.z; r[7] = (bf16_t)b.w;
  return r;
}

// ---------------- fp32 -> bf16 conversion (weights only) --------------------
__global__ void __launch_bounds__(256) cvt_bf16_seg_kernel(
    const float* __restrict__ s0, const float* __restrict__ s1,
    const float* __restrict__ s2, const float* __restrict__ s3,
    unsigned short* __restrict__ out, int lg) {
  int i = blockIdx.x * blockDim.x + threadIdx.x;
  int seg = i >> lg, j = i & ((1 << lg) - 1);
  const float* src = seg == 0 ? s0 : seg == 1 ? s1 : seg == 2 ? s2 : s3;
  float4 v = reinterpret_cast<const float4*>(src)[j];
  ushort4 o;
  o.x = f2bf(v.x); o.y = f2bf(v.y); o.z = f2bf(v.z); o.w = f2bf(v.w);
  reinterpret_cast<ushort4*>(out)[i] = o;
}

// ---------------- GEMM: C[m][n] = (sum_k A[m][k]*W[n][k] + bias[n]) * scale ----
// W: [N][K] bf16 row-major (i.e. X @ W^T). 128x128 tile, BK=32, 256 threads
// (4 waves, 2x2), 16 16x16x32 MFMA per wave per K-step.
//
// R16: __launch_bounds__(256, 4) for QKV. Occupancy audit: VGPR_Count=76 is
//   ARCH regs only; acc[4][4] = 64 AGPR, and gfx950's unified file makes the
//   true budget 140 -> 3 waves/SIMD = 37.5% theoretical -- matching the
//   measured 32% that did NOT move when LDS went 48->32KB. Registers, not
//   LDS, cap QKV. min-waves=4 forces arch+acc <= 128 (shave ~12 arch regs
//   via remat). Tripwire: if it spills instead, FETCH balloons (R3
//   signature) -> revert. Wo keeps an unconstraining bound (LDS-capped at 3
//   blocks by its 48KB 3-buffer layout anyway).
//
// QKV=true (fp32-A, cvt fused): 2 LDS buffers (32KB); W depth-1, A-reg
//   depth-2 staging (R15 schedule, counted vmcnt(4), never 0 mid-loop).
// QKV=false (bf16-A, output proj): R7 counted scheme, 3 buffers.
// BK=32 row stride = 64 B -> 4-slot XOR swizzle (SOURCE col slot ^ (row&3),
// read byte ^ ((l15&3)<<4)). XCD swizzle per-z-slice.
// QKV z=2 (V) stored TRANSPOSED+kv-field-swapped (bits [5:4]<->[3:2] of s&63).
template <bool QKV>
__global__ void __launch_bounds__(256, QKV ? 4 : 2) gemm_dbuf_kernel(
    const void* __restrict__ A0v, const void* __restrict__ A1v,
    const void* __restrict__ A2v,
    const unsigned short* __restrict__ W0, const unsigned short* __restrict__ W1,
    const unsigned short* __restrict__ W2,
    const float* __restrict__ b0, const float* __restrict__ b1,
    const float* __restrict__ b2,
    void* __restrict__ C0, void* __restrict__ C1, void* __restrict__ C2,
    int M, int N, int K, float scale0) {
  __shared__ unsigned short lA[QKV ? 2 : 3][128 * 32];
  __shared__ unsigned short lB[QKV ? 2 : 3][128 * 32];
  const int t = threadIdx.x;
  const int wv = t >> 6, ln = t & 63;
  const int l15 = ln & 15, lhi = ln >> 4;

  const void* Av; const unsigned short* W;
  const float* bias; void* Cout; float scale; int mode;
  if (QKV) {
    const int z = blockIdx.z;
    Av = z == 0 ? A0v : z == 1 ? A1v : A2v;
    W = z == 0 ? W0 : z == 1 ? W1 : W2;
    bias = z == 0 ? b0 : z == 1 ? b1 : b2;
    Cout = z == 0 ? C0 : z == 1 ? C1 : C2;
    scale = z == 0 ? scale0 : 1.0f;
    mode = z == 2 ? 2 : 1;
  } else {
    Av = A0v; W = W0; bias = b0; Cout = C0; scale = scale0; mode = 0;
  }

  // XCD-chunked remap (bijective; per-slice grid = 512, multiple of 8)
  const int nwg = gridDim.x * gridDim.y;
  const int hw = blockIdx.y * gridDim.x + blockIdx.x;
  const int chunk = nwg >> 3;
  const int swzid = (hw & 7) * chunk + (hw >> 3);
  const int m0 = (swzid / gridDim.x) * 128, n0 = (swzid % gridDim.x) * 128;
  const int wr = wv >> 1, wc = wv & 1;
  const int swzR = (l15 & 3) << 4; // frag-read byte XOR (row&3 == l15&3)

  const int rowA = t >> 2;
  const int colS = ((t & 3) ^ (rowA & 3)) * 8;
  const unsigned short* wS = W + (size_t)(n0 + rowA) * K + colS;
  const size_t rstep = (size_t)64 * K;
  const int d0 = t * 16, d1 = 4096 + t * 16;
  const float* aF = QKV ? (const float*)Av + (size_t)(m0 + rowA) * K + colS : nullptr;
  const unsigned short* aB =
      QKV ? nullptr : (const unsigned short*)Av + (size_t)(m0 + rowA) * K + colS;

  f32x4 acc[4][4] = {};
  const int NK = K >> 5; // 32

#define WST(bi, k0_)                                           \
  do {                                                         \
    gload_lds16(wS + (k0_), (char*)lB[bi] + d0);               \
    gload_lds16(wS + rstep + (k0_), (char*)lB[bi] + d1);       \
  } while (0)

#define MFMA_BLOCK(cur_)                                                        \
  do {                                                                          \
    bf16x8 af[4], bfr[4];                                                       \
    _Pragma("unroll") for (int i = 0; i < 4; ++i)                               \
      af[i] = *reinterpret_cast<const bf16x8*>(                                 \
          (char*)lA[cur_] + (((wr * 64 + i * 16 + l15) * 64 + lhi * 16) ^ swzR));\
    _Pragma("unroll") for (int j = 0; j < 4; ++j)                               \
      bfr[j] = *reinterpret_cast<const bf16x8*>(                                \
          (char*)lB[cur_] + (((wc * 64 + j * 16 + l15) * 64 + lhi * 16) ^ swzR));\
    _Pragma("unroll") for (int i = 0; i < 4; ++i)                               \
      _Pragma("unroll") for (int j = 0; j < 4; ++j)                             \
        acc[i][j] = __builtin_amdgcn_mfma_f32_16x16x32_bf16(af[i], bfr[j],      \
                                                            acc[i][j], 0, 0, 0);\
  } while (0)

  if (QKV) {
    float4 a0, a1, a2, a3;      // aC: A-tile for NEXT iteration's ds_write
    float4 n0_, n1_, n2_, n3_;  // aN: loads in flight for tile tk+2
#define ALD(k0_)                                               \
  do {                                                         \
    const float* p = aF + (k0_);                               \
    a0 = *(const float4*)(p);     a1 = *(const float4*)(p + 4);\
    a2 = *(const float4*)(p + rstep); a3 = *(const float4*)(p + rstep + 4);\
  } while (0)
#define ALDN(k0_)                                              \
  do {                                                         \
    const float* p = aF + (k0_);                               \
    n0_ = *(const float4*)(p);     n1_ = *(const float4*)(p + 4);\
    n2_ = *(const float4*)(p + rstep); n3_ = *(const float4*)(p + rstep + 4);\
  } while (0)
#define AWR(bi)                                                \
  do {                                                         \
    *reinterpret_cast<bf16x8*>((char*)lA[bi] + d0) = cvt8(a0, a1);\
    *reinterpret_cast<bf16x8*>((char*)lA[bi] + d1) = cvt8(a2, a3);\
  } while (0)
    // prologue: tile0 A+W staged into buf0; aC = A(tile 1) in flight.
    WST(0, 0);
    ALD(0);
    AWR(0);            // implicit vmcnt wait for A(0) loads
    ALD(32);           // aC = A(tile 1); in flight: W(0) (<=2) + A(1) 4
    asm volatile("s_waitcnt vmcnt(4) lgkmcnt(0)" ::: "memory"); // drain W(0)
    __builtin_amdgcn_s_barrier();
    __builtin_amdgcn_sched_barrier(0);

    for (int tk = 0; tk < NK; ++tk) {
      const int cur = tk & 1, nxt = cur ^ 1;
      const bool hn = (tk + 1 < NK), hn2 = (tk + 2 < NK);
      if (hn) WST(nxt, (tk + 1) * 32);  // depth-1 W -> other buffer
      if (hn2) ALDN((tk + 2) * 32);     // depth-2 A -> regs
      __builtin_amdgcn_sched_barrier(0); // keep load-issue above the MFMAs
      MFMA_BLOCK(cur);
      if (hn) AWR(nxt); // consumes aC=A(tk+1) (loaded LAST iter; implicit
                        // vmcnt<=6 leaves this iter's 6 loads in flight)
      if (hn2) { a0 = n0_; a1 = n1_; a2 = n2_; a3 = n3_; }
      if (hn2)
        asm volatile("s_waitcnt vmcnt(4) lgkmcnt(0)" ::: "memory"); // drain W(tk+1)
      else
        asm volatile("s_waitcnt vmcnt(0) lgkmcnt(0)" ::: "memory");
      __builtin_amdgcn_s_barrier(); // publishes buf nxt (W + A landed)
      __builtin_amdgcn_sched_barrier(0);
    }
#undef ALD
#undef ALDN
#undef AWR
  } else {
    // bf16-A output projection: R7 counted scheme (4 gload_lds/iter, vmcnt(4))
#define AST(bi, k0_)                                           \
  do {                                                         \
    gload_lds16(aB + (k0_), (char*)lA[bi] + d0);               \
    gload_lds16(aB + rstep + (k0_), (char*)lA[bi] + d1);       \
  } while (0)
    AST(0, 0); WST(0, 0);
    AST(1, 32); WST(1, 32);
    for (int tk = 0; tk < NK; ++tk) {
      const int cur = tk % 3;
      if (tk == NK - 1)
        asm volatile("s_waitcnt vmcnt(0)" ::: "memory");
      else
        asm volatile("s_waitcnt vmcnt(4)" ::: "memory");
      __builtin_amdgcn_s_barrier();
      __builtin_amdgcn_sched_barrier(0);
      if (tk + 2 < NK) {
        AST((tk + 2) % 3, (tk + 2) * 32);
        WST((tk + 2) % 3, (tk + 2) * 32);
      }
      MFMA_BLOCK(cur);
    }
#undef AST
  }
#undef WST
#undef MFMA_BLOCK

#pragma unroll
  for (int i = 0; i < 4; ++i)
#pragma unroll
    for (int j = 0; j < 4; ++j) {
      int n = n0 + wc * 64 + j * 16 + l15;
      float bv = bias[n];
      if (QKV && mode == 2) {
        int mb = m0 + wr * 64 + i * 16 + lhi * 4; // 4 consecutive m = consecutive s
        int sl = mb & (Sc - 1);
        // field-swap bits [5:4]<->[3:2] (low 2 bits untouched -> ushort4 ok)
        int pl = (sl & ~60) | ((sl & 48) >> 2) | ((sl & 12) << 2);
        ushort4 ov;
        ov.x = f2bf((acc[i][j][0] + bv) * scale);
        ov.y = f2bf((acc[i][j][1] + bv) * scale);
        ov.z = f2bf((acc[i][j][2] + bv) * scale);
        ov.w = f2bf((acc[i][j][3] + bv) * scale);
        *reinterpret_cast<ushort4*>((unsigned short*)Cout +
            ((size_t)(mb >> 11) * Dc + n) * Sc + pl) = ov;
      } else {
#pragma unroll
        for (int jj = 0; jj < 4; ++jj) {
          int m = m0 + wr * 64 + i * 16 + lhi * 4 + jj;
          float v = (acc[i][j][jj] + bv) * scale;
          if (QKV)
            ((unsigned short*)Cout)[(size_t)m * N + n] = f2bf(v);
          else
            ((float*)Cout)[(size_t)m * N + n] = v;
        }
      }
    }
}

// ---------------- Flash attention ----------------
// (R13 configuration, best measured ~88us: QBLK=256 dual-sub fragment
// hoisting, KVBLK=128 dbuf 64KB, no-max softmax, XCD-affinity remap.
// R14's KVBLK=64/4-block variant regressed: barrier/issue-rate floor.)
__global__ void __launch_bounds__(512, 4) attn_kernel(
    const unsigned short* __restrict__ Q, const unsigned short* __restrict__ Kk,
    const unsigned short* __restrict__ Vt, unsigned short* __restrict__ X) {
  __shared__ unsigned short lK[2][128 * 64];  // [kv][dk], XOR-swizzled
  __shared__ unsigned short lVT[2][64 * 128]; // [dk][swapped-kv], XOR-swizzled
  const int t = threadIdx.x;
  const int wv = t >> 6, ln = t & 63;
  const int l15 = ln & 15, lhi = ln >> 4;
  const int lin = blockIdx.x + (blockIdx.y << 3) + (blockIdx.z << 7); // [0,512)
  const int jb = lin >> 3;
  const int p = (lin & 7) * 8 + (jb >> 3); // panel = h + 16b, [0,64)
  const int q0 = (jb & 7) * 256;
  const int h = p & 15, b = p >> 4;
  const size_t base = (size_t)b * Sc * Dc;
  const int hoff = h * DKc;

  // Q for this wave's 32 q-rows (2 subs x 16)
  bf16x8 qf[2][2];
#pragma unroll
  for (int s = 0; s < 2; ++s) {
    const unsigned short* qp =
        Q + base + (size_t)(q0 + wv * 32 + s * 16 + l15) * Dc + hoff + lhi * 8;
    qf[s][0] = *reinterpret_cast<const bf16x8*>(qp);
    qf[s][1] = *reinterpret_cast<const bf16x8*>(qp + 32);
  }

  const int kvr = t >> 3;
  const int kcol = ((t & 7) * 8) ^ ((kvr & 7) << 3);
  const unsigned short* kS = Kk + base + (size_t)kvr * Dc + hoff + kcol;
  const int vdk = t >> 4;
  const int vkv = ((t & 15) * 8) ^ ((vdk & 7) << 3);
  const unsigned short* vS = Vt + ((size_t)b * Dc + hoff + vdk) * Sc + vkv;

  f32x4 xacc[2][4] = {}; // [sub][dt]: out rows lhi*4+jj, cols dt*16+l15
  f32x4 lsum[2] = {};    // [sub]: row sums (ones-MFMA)
  const int swzK = (l15 & 7) << 4;

  bf16x4 ones4;
#pragma unroll
  for (int i = 0; i < 4; ++i) ones4[i] = (bf16_t)1.0f;

#define DSTAGE(bi, kv0_)                                                        \
  do {                                                                          \
    gload_lds16(kS + (size_t)(kv0_)*Dc, (char*)lK[bi] + t * 16);                \
    gload_lds16(kS + (size_t)((kv0_) + 64) * Dc, (char*)lK[bi] + 8192 + t * 16);\
    gload_lds16(vS + (kv0_), (char*)lVT[bi] + t * 16);                          \
    gload_lds16(vS + (size_t)32 * Sc + (kv0_), (char*)lVT[bi] + 8192 + t * 16); \
  } while (0)

  DSTAGE(0, 0);
  asm volatile("s_waitcnt vmcnt(0)" ::: "memory");
  __builtin_amdgcn_s_barrier();
  __builtin_amdgcn_sched_barrier(0);

  const int NT2 = Sc / 128; // 16
  for (int tt = 0; tt < NT2; ++tt) {
    const int cur = tt & 1;
    if (tt + 1 < NT2) DSTAGE(cur ^ 1, (tt + 1) * 128);

    const char* K_ = (const char*)lK[cur];
    const char* VT_ = (const char*)lVT[cur];

#pragma unroll
    for (int s64 = 0; s64 < 2; ++s64) {
#pragma unroll
      for (int sel = 0; sel < 2; ++sel) {
        bf16x4 pa[2][2]; // [sub][ct_i]
        __builtin_amdgcn_s_setprio(1);
#pragma unroll
        for (int ci = 0; ci < 2; ++ci) {
          const int ct = sel * 2 + ci;
          // one kf pair serves BOTH subs (fragment is q-row-independent)
          bf16x8 kf0 = *reinterpret_cast<const bf16x8*>(
              K_ + (((s64 * 64 + ct * 16 + l15) * 128 + lhi * 16) ^ swzK));
          bf16x8 kf1 = *reinterpret_cast<const bf16x8*>(
              K_ + (((s64 * 64 + ct * 16 + l15) * 128 + 64 + lhi * 16) ^ swzK));
#pragma unroll
          for (int s = 0; s < 2; ++s) {
            f32x4 z = {};
            z = __builtin_amdgcn_mfma_f32_16x16x32_bf16(kf0, qf[s][0], z, 0, 0, 0);
            z = __builtin_amdgcn_mfma_f32_16x16x32_bf16(kf1, qf[s][1], z, 0, 0, 0);
#pragma unroll
            for (int jj = 0; jj < 4; ++jj)
              pa[s][ci][jj] = (bf16_t)fexp2(z[jj]);
            lsum[s] = mfma16(pa[s][ci], ones4, lsum[s]);
          }
        }
        __builtin_amdgcn_s_setprio(0);
        // PV: one Vt b128 serves both ct-halves AND both subs
#pragma unroll
        for (int dt = 0; dt < 4; ++dt) {
          bf16x8 vb2 = *reinterpret_cast<const bf16x8*>(
              VT_ + (((dt * 16 + l15) * 256 + s64 * 128 + lhi * 32 + sel * 16) ^ swzK));
          bf16x4 vlo = __builtin_shufflevector(vb2, vb2, 0, 1, 2, 3);
          bf16x4 vhi = __builtin_shufflevector(vb2, vb2, 4, 5, 6, 7);
#pragma unroll
          for (int s = 0; s < 2; ++s) {
            xacc[s][dt] = mfma16(pa[s][0], vlo, xacc[s][dt]);
            xacc[s][dt] = mfma16(pa[s][1], vhi, xacc[s][dt]);
          }
        }
      }
    }

    asm volatile("s_waitcnt vmcnt(0)" ::: "memory");
    __builtin_amdgcn_s_barrier();
    __builtin_amdgcn_sched_barrier(0);
  }
#undef DSTAGE

#pragma unroll
  for (int s = 0; s < 2; ++s) {
    float iO[4];
#pragma unroll
    for (int jj = 0; jj < 4; ++jj) iO[jj] = 1.0f / lsum[s][jj];
    unsigned short* xp =
        X + base + (size_t)(q0 + wv * 32 + s * 16) * Dc + hoff;
#pragma unroll
    for (int dt = 0; dt < 4; ++dt)
#pragma unroll
      for (int jj = 0; jj < 4; ++jj) {
        int r = lhi * 4 + jj;
        xp[(size_t)r * Dc + dt * 16 + l15] = f2bf(xacc[s][dt][jj] * iO[jj]);
      }
  }
}

// ---------------- launch ----------------
extern "C" void kernel_launch(void* const* d_in, const int* in_sizes, int n_in,
                              void* d_out, int out_size, void* d_ws, size_t ws_size,
                              hipStream_t stream) {
  const float* query = (const float*)d_in[0];
  const float* key   = (const float*)d_in[1];
  const float* value = (const float*)d_in[2];
  const float* Wq = (const float*)d_in[3];
  const float* bq = (const float*)d_in[4];
  const float* Wk = (const float*)d_in[5];
  const float* bk = (const float*)d_in[6];
  const float* Wv = (const float*)d_in[7];
  const float* bv = (const float*)d_in[8];
  const float* Wo = (const float*)d_in[9];
  const float* bo = (const float*)d_in[10];

  const size_t NBS = (size_t)Mrows * Dc; // 8388608
  const size_t NW  = (size_t)Dc * Dc;    // 1048576
  unsigned short* bWq  = (unsigned short*)d_ws;
  unsigned short* bWk  = bWq + NW;
  unsigned short* bWv  = bWk + NW;
  unsigned short* bWo  = bWv + NW;
  unsigned short* Qp   = bWo + NW;
  unsigned short* Kp   = Qp + NBS;
  unsigned short* Vtp  = Kp + NBS; // V projection, TRANSPOSED + field-swapped
  unsigned short* Xp   = Vtp + NBS;

  // weights: 4 contiguous segments (bWq..bWo); lg = log2(NW/4) = 18
  // (input fp32->bf16 cvt is fused into the QKV GEMM's A-staging)
  cvt_bf16_seg_kernel<<<(int)(4 * NW / 1024), 256, 0, stream>>>(
      Wq, Wk, Wv, Wo, bWq, 18);

  // fused Q/K/V projections, fp32-A: z selects; Q prescale folds 1/sqrt(DK)
  // AND log2(e) (attn softmax runs in exp2 domain)
  gemm_dbuf_kernel<true><<<dim3(Dc / 128, Mrows / 128, 3), 256, 0, stream>>>(
      query, key, value, bWq, bWk, bWv, bq, bk, bv, Qp, Kp, Vtp,
      Mrows, Dc, Dc, 0.125f * 1.44269504088896340736f);

  attn_kernel<<<dim3(Sc / 256, Hc, Bc), 512, 0, stream>>>(Qp, Kp, Vtp, Xp);

  gemm_dbuf_kernel<false><<<dim3(Dc / 128, Mrows / 128, 1), 256, 0, stream>>>(
      Xp, nullptr, nullptr, bWo, nullptr, nullptr, bo, nullptr, nullptr,
      d_out, nullptr, nullptr, Mrows, Dc, Dc, 1.0f);
}

// Round 17
// 193.510 us; speedup vs baseline: 1.2502x; 1.2502x over previous
//
#include <hip/hip_runtime.h>
#include <stdint.h>

#define DEV static __device__ __forceinline__

typedef __bf16 bf16_t;
typedef bf16_t bf16x8 __attribute__((ext_vector_type(8)));
typedef bf16_t bf16x4 __attribute__((ext_vector_type(4)));
typedef float f32x4 __attribute__((ext_vector_type(4)));

static constexpr int Bc = 4, Sc = 2048, Dc = 1024, Hc = 16, DKc = 64;
static constexpr int Mrows = Bc * Sc; // 8192

DEV unsigned short f2bf(float f) {
  unsigned int u = __float_as_uint(f);
  u += 0x7fffu + ((u >> 16) & 1u);
  return (unsigned short)(u >> 16);
}

DEV float fexp2(float x) {
#if __has_builtin(__builtin_amdgcn_exp2f)
  return __builtin_amdgcn_exp2f(x); // single v_exp_f32
#else
  return exp2f(x);
#endif
}

// 16x16x16 bf16 MFMA (K=16): A-frag k-granularity = lhi*4 -- matches the
// swapped-QK^T D-layout exactly, so P feeds PV straight from registers.
#if __has_builtin(__builtin_amdgcn_mfma_f32_16x16x16_bf16)
DEV f32x4 mfma16(bf16x4 a, bf16x4 b, f32x4 c) {
  return __builtin_amdgcn_mfma_f32_16x16x16_bf16(a, b, c, 0, 0, 0);
}
#elif __has_builtin(__builtin_amdgcn_mfma_f32_16x16x16bf16_1k)
typedef short s16x4 __attribute__((ext_vector_type(4)));
DEV f32x4 mfma16(bf16x4 a, bf16x4 b, f32x4 c) {
  union U { bf16x4 h; s16x4 s; };
  U ua, ub; ua.h = a; ub.h = b;
  return __builtin_amdgcn_mfma_f32_16x16x16bf16_1k(ua.s, ub.s, c, 0, 0, 0);
}
#else
DEV f32x4 mfma16(bf16x4 a, bf16x4 b, f32x4 c) {
  asm("v_mfma_f32_16x16x16_bf16 %0, %1, %2, %0" : "+v"(c) : "v"(a), "v"(b));
  return c;
}
#endif

DEV void gload_lds16(const void* g, void* l) {
  __builtin_amdgcn_global_load_lds(
      (const __attribute__((address_space(1))) void*)g,
      (__attribute__((address_space(3))) void*)l, 16, 0, 0);
}

// 8 fp32 -> bf16x8 (RTNE; compiler emits v_cvt_pk_bf16_f32 pairs)
DEV bf16x8 cvt8(float4 a, float4 b) {
  bf16x8 r;
  r[0] = (bf16_t)a.x; r[1] = (bf16_t)a.y; r[2] = (bf16_t)a.z; r[3] = (bf16_t)a.w;
  r[4] = (bf16_t)b.x; r[5] = (bf16_t)b.y; r[6] = (bf16_t)b.z; r[7] = (bf16_t)b.w;
  return r;
}

// ---------------- fp32 -> bf16 conversion (weights only) --------------------
__global__ void __launch_bounds__(256) cvt_bf16_seg_kernel(
    const float* __restrict__ s0, const float* __restrict__ s1,
    const float* __restrict__ s2, const float* __restrict__ s3,
    unsigned short* __restrict__ out, int lg) {
  int i = blockIdx.x * blockDim.x + threadIdx.x;
  int seg = i >> lg, j = i & ((1 << lg) - 1);
  const float* src = seg == 0 ? s0 : seg == 1 ? s1 : seg == 2 ? s2 : s3;
  float4 v = reinterpret_cast<const float4*>(src)[j];
  ushort4 o;
  o.x = f2bf(v.x); o.y = f2bf(v.y); o.z = f2bf(v.z); o.w = f2bf(v.w);
  reinterpret_cast<ushort4*>(out)[i] = o;
}

// ---------------- GEMM: C[m][n] = (sum_k A[m][k]*W[n][k] + bias[n]) * scale ----
// W: [N][K] bf16 row-major (i.e. X @ W^T). 128x128 tile, BK=32, 256 threads
// (4 waves, 2x2), 16 16x16x32 MFMA per wave per K-step.
//
// R17 = R15 EXACT REVERT (best measured: 194.6us total). R16's
// __launch_bounds__(256,4) forced arch VGPR 76->64 and SPILLED (WRITE_SIZE
// 55->72MB, MfmaUtil 16->12, QKV 126->176us). Ledger: true footprint =
// 76 arch + 64 acc(AGPR, unified file) = 140 regs -> 3 waves/SIMD is this
// structure's HARD occupancy ceiling; R11/R14/R16 all regressed trying to
// move it. R15 is the measured optimum of this decomposition.
//
// QKV=true (fp32-A, cvt fused): 2 LDS buffers (32KB); W depth-1, A-reg
//   depth-2 staging; counted vmcnt(4) (drains W(tk+1), keeps A(tk+2) in
//   flight); vmcnt(0) only when nothing newer exists (tk>=NK-2).
// QKV=false (bf16-A, output proj): R7 counted scheme, 3 buffers, vmcnt(4).
// BK=32 row stride = 64 B -> 4-slot XOR swizzle (SOURCE col slot ^ (row&3),
// read byte ^ ((l15&3)<<4)). XCD swizzle per-z-slice.
// QKV z=2 (V) stored TRANSPOSED+kv-field-swapped (bits [5:4]<->[3:2] of s&63).
template <bool QKV>
__global__ void __launch_bounds__(256) gemm_dbuf_kernel(
    const void* __restrict__ A0v, const void* __restrict__ A1v,
    const void* __restrict__ A2v,
    const unsigned short* __restrict__ W0, const unsigned short* __restrict__ W1,
    const unsigned short* __restrict__ W2,
    const float* __restrict__ b0, const float* __restrict__ b1,
    const float* __restrict__ b2,
    void* __restrict__ C0, void* __restrict__ C1, void* __restrict__ C2,
    int M, int N, int K, float scale0) {
  __shared__ unsigned short lA[QKV ? 2 : 3][128 * 32];
  __shared__ unsigned short lB[QKV ? 2 : 3][128 * 32];
  const int t = threadIdx.x;
  const int wv = t >> 6, ln = t & 63;
  const int l15 = ln & 15, lhi = ln >> 4;

  const void* Av; const unsigned short* W;
  const float* bias; void* Cout; float scale; int mode;
  if (QKV) {
    const int z = blockIdx.z;
    Av = z == 0 ? A0v : z == 1 ? A1v : A2v;
    W = z == 0 ? W0 : z == 1 ? W1 : W2;
    bias = z == 0 ? b0 : z == 1 ? b1 : b2;
    Cout = z == 0 ? C0 : z == 1 ? C1 : C2;
    scale = z == 0 ? scale0 : 1.0f;
    mode = z == 2 ? 2 : 1;
  } else {
    Av = A0v; W = W0; bias = b0; Cout = C0; scale = scale0; mode = 0;
  }

  // XCD-chunked remap (bijective; per-slice grid = 512, multiple of 8)
  const int nwg = gridDim.x * gridDim.y;
  const int hw = blockIdx.y * gridDim.x + blockIdx.x;
  const int chunk = nwg >> 3;
  const int swzid = (hw & 7) * chunk + (hw >> 3);
  const int m0 = (swzid / gridDim.x) * 128, n0 = (swzid % gridDim.x) * 128;
  const int wr = wv >> 1, wc = wv & 1;
  const int swzR = (l15 & 3) << 4; // frag-read byte XOR (row&3 == l15&3)

  const int rowA = t >> 2;
  const int colS = ((t & 3) ^ (rowA & 3)) * 8;
  const unsigned short* wS = W + (size_t)(n0 + rowA) * K + colS;
  const size_t rstep = (size_t)64 * K;
  const int d0 = t * 16, d1 = 4096 + t * 16;
  const float* aF = QKV ? (const float*)Av + (size_t)(m0 + rowA) * K + colS : nullptr;
  const unsigned short* aB =
      QKV ? nullptr : (const unsigned short*)Av + (size_t)(m0 + rowA) * K + colS;

  f32x4 acc[4][4] = {};
  const int NK = K >> 5; // 32

#define WST(bi, k0_)                                           \
  do {                                                         \
    gload_lds16(wS + (k0_), (char*)lB[bi] + d0);               \
    gload_lds16(wS + rstep + (k0_), (char*)lB[bi] + d1);       \
  } while (0)

#define MFMA_BLOCK(cur_)                                                        \
  do {                                                                          \
    bf16x8 af[4], bfr[4];                                                       \
    _Pragma("unroll") for (int i = 0; i < 4; ++i)                               \
      af[i] = *reinterpret_cast<const bf16x8*>(                                 \
          (char*)lA[cur_] + (((wr * 64 + i * 16 + l15) * 64 + lhi * 16) ^ swzR));\
    _Pragma("unroll") for (int j = 0; j < 4; ++j)                               \
      bfr[j] = *reinterpret_cast<const bf16x8*>(                                \
          (char*)lB[cur_] + (((wc * 64 + j * 16 + l15) * 64 + lhi * 16) ^ swzR));\
    _Pragma("unroll") for (int i = 0; i < 4; ++i)                               \
      _Pragma("unroll") for (int j = 0; j < 4; ++j)                             \
        acc[i][j] = __builtin_amdgcn_mfma_f32_16x16x32_bf16(af[i], bfr[j],      \
                                                            acc[i][j], 0, 0, 0);\
  } while (0)

  if (QKV) {
    float4 a0, a1, a2, a3;      // aC: A-tile for NEXT iteration's ds_write
    float4 n0_, n1_, n2_, n3_;  // aN: loads in flight for tile tk+2
#define ALD(k0_)                                               \
  do {                                                         \
    const float* p = aF + (k0_);                               \
    a0 = *(const float4*)(p);     a1 = *(const float4*)(p + 4);\
    a2 = *(const float4*)(p + rstep); a3 = *(const float4*)(p + rstep + 4);\
  } while (0)
#define ALDN(k0_)                                              \
  do {                                                         \
    const float* p = aF + (k0_);                               \
    n0_ = *(const float4*)(p);     n1_ = *(const float4*)(p + 4);\
    n2_ = *(const float4*)(p + rstep); n3_ = *(const float4*)(p + rstep + 4);\
  } while (0)
#define AWR(bi)                                                \
  do {                                                         \
    *reinterpret_cast<bf16x8*>((char*)lA[bi] + d0) = cvt8(a0, a1);\
    *reinterpret_cast<bf16x8*>((char*)lA[bi] + d1) = cvt8(a2, a3);\
  } while (0)
    // prologue: tile0 A+W staged into buf0; aC = A(tile 1) in flight.
    WST(0, 0);
    ALD(0);
    AWR(0);            // implicit vmcnt wait for A(0) loads
    ALD(32);           // aC = A(tile 1); in flight: W(0) (<=2) + A(1) 4
    asm volatile("s_waitcnt vmcnt(4) lgkmcnt(0)" ::: "memory"); // drain W(0)
    __builtin_amdgcn_s_barrier();
    __builtin_amdgcn_sched_barrier(0);

    for (int tk = 0; tk < NK; ++tk) {
      const int cur = tk & 1, nxt = cur ^ 1;
      const bool hn = (tk + 1 < NK), hn2 = (tk + 2 < NK);
      if (hn) WST(nxt, (tk + 1) * 32);  // depth-1 W -> other buffer
      if (hn2) ALDN((tk + 2) * 32);     // depth-2 A -> regs
      __builtin_amdgcn_sched_barrier(0); // keep load-issue above the MFMAs
      MFMA_BLOCK(cur);
      if (hn) AWR(nxt); // consumes aC=A(tk+1) (loaded LAST iter; implicit
                        // vmcnt<=6 leaves this iter's 6 loads in flight)
      if (hn2) { a0 = n0_; a1 = n1_; a2 = n2_; a3 = n3_; }
      if (hn2)
        asm volatile("s_waitcnt vmcnt(4) lgkmcnt(0)" ::: "memory"); // drain W(tk+1)
      else
        asm volatile("s_waitcnt vmcnt(0) lgkmcnt(0)" ::: "memory");
      __builtin_amdgcn_s_barrier(); // publishes buf nxt (W + A landed)
      __builtin_amdgcn_sched_barrier(0);
    }
#undef ALD
#undef ALDN
#undef AWR
  } else {
    // bf16-A output projection: R7 counted scheme (4 gload_lds/iter, vmcnt(4))
#define AST(bi, k0_)                                           \
  do {                                                         \
    gload_lds16(aB + (k0_), (char*)lA[bi] + d0);               \
    gload_lds16(aB + rstep + (k0_), (char*)lA[bi] + d1);       \
  } while (0)
    AST(0, 0); WST(0, 0);
    AST(1, 32); WST(1, 32);
    for (int tk = 0; tk < NK; ++tk) {
      const int cur = tk % 3;
      if (tk == NK - 1)
        asm volatile("s_waitcnt vmcnt(0)" ::: "memory");
      else
        asm volatile("s_waitcnt vmcnt(4)" ::: "memory");
      __builtin_amdgcn_s_barrier();
      __builtin_amdgcn_sched_barrier(0);
      if (tk + 2 < NK) {
        AST((tk + 2) % 3, (tk + 2) * 32);
        WST((tk + 2) % 3, (tk + 2) * 32);
      }
      MFMA_BLOCK(cur);
    }
#undef AST
  }
#undef WST
#undef MFMA_BLOCK

#pragma unroll
  for (int i = 0; i < 4; ++i)
#pragma unroll
    for (int j = 0; j < 4; ++j) {
      int n = n0 + wc * 64 + j * 16 + l15;
      float bv = bias[n];
      if (QKV && mode == 2) {
        int mb = m0 + wr * 64 + i * 16 + lhi * 4; // 4 consecutive m = consecutive s
        int sl = mb & (Sc - 1);
        // field-swap bits [5:4]<->[3:2] (low 2 bits untouched -> ushort4 ok)
        int pl = (sl & ~60) | ((sl & 48) >> 2) | ((sl & 12) << 2);
        ushort4 ov;
        ov.x = f2bf((acc[i][j][0] + bv) * scale);
        ov.y = f2bf((acc[i][j][1] + bv) * scale);
        ov.z = f2bf((acc[i][j][2] + bv) * scale);
        ov.w = f2bf((acc[i][j][3] + bv) * scale);
        *reinterpret_cast<ushort4*>((unsigned short*)Cout +
            ((size_t)(mb >> 11) * Dc + n) * Sc + pl) = ov;
      } else {
#pragma unroll
        for (int jj = 0; jj < 4; ++jj) {
          int m = m0 + wr * 64 + i * 16 + lhi * 4 + jj;
          float v = (acc[i][j][jj] + bv) * scale;
          if (QKV)
            ((unsigned short*)Cout)[(size_t)m * N + n] = f2bf(v);
          else
            ((float*)Cout)[(size_t)m * N + n] = v;
        }
      }
    }
}

// ---------------- Flash attention ----------------
// (R13 configuration, best measured ~88us: QBLK=256 dual-sub fragment
// hoisting, KVBLK=128 dbuf 64KB, no-max softmax, XCD-affinity remap.
// R14's KVBLK=64/4-block variant regressed: barrier/issue-rate floor.)
__global__ void __launch_bounds__(512, 4) attn_kernel(
    const unsigned short* __restrict__ Q, const unsigned short* __restrict__ Kk,
    const unsigned short* __restrict__ Vt, unsigned short* __restrict__ X) {
  __shared__ unsigned short lK[2][128 * 64];  // [kv][dk], XOR-swizzled
  __shared__ unsigned short lVT[2][64 * 128]; // [dk][swapped-kv], XOR-swizzled
  const int t = threadIdx.x;
  const int wv = t >> 6, ln = t & 63;
  const int l15 = ln & 15, lhi = ln >> 4;
  const int lin = blockIdx.x + (blockIdx.y << 3) + (blockIdx.z << 7); // [0,512)
  const int jb = lin >> 3;
  const int p = (lin & 7) * 8 + (jb >> 3); // panel = h + 16b, [0,64)
  const int q0 = (jb & 7) * 256;
  const int h = p & 15, b = p >> 4;
  const size_t base = (size_t)b * Sc * Dc;
  const int hoff = h * DKc;

  // Q for this wave's 32 q-rows (2 subs x 16)
  bf16x8 qf[2][2];
#pragma unroll
  for (int s = 0; s < 2; ++s) {
    const unsigned short* qp =
        Q + base + (size_t)(q0 + wv * 32 + s * 16 + l15) * Dc + hoff + lhi * 8;
    qf[s][0] = *reinterpret_cast<const bf16x8*>(qp);
    qf[s][1] = *reinterpret_cast<const bf16x8*>(qp + 32);
  }

  const int kvr = t >> 3;
  const int kcol = ((t & 7) * 8) ^ ((kvr & 7) << 3);
  const unsigned short* kS = Kk + base + (size_t)kvr * Dc + hoff + kcol;
  const int vdk = t >> 4;
  const int vkv = ((t & 15) * 8) ^ ((vdk & 7) << 3);
  const unsigned short* vS = Vt + ((size_t)b * Dc + hoff + vdk) * Sc + vkv;

  f32x4 xacc[2][4] = {}; // [sub][dt]: out rows lhi*4+jj, cols dt*16+l15
  f32x4 lsum[2] = {};    // [sub]: row sums (ones-MFMA)
  const int swzK = (l15 & 7) << 4;

  bf16x4 ones4;
#pragma unroll
  for (int i = 0; i < 4; ++i) ones4[i] = (bf16_t)1.0f;

#define DSTAGE(bi, kv0_)                                                        \
  do {                                                                          \
    gload_lds16(kS + (size_t)(kv0_)*Dc, (char*)lK[bi] + t * 16);                \
    gload_lds16(kS + (size_t)((kv0_) + 64) * Dc, (char*)lK[bi] + 8192 + t * 16);\
    gload_lds16(vS + (kv0_), (char*)lVT[bi] + t * 16);                          \
    gload_lds16(vS + (size_t)32 * Sc + (kv0_), (char*)lVT[bi] + 8192 + t * 16); \
  } while (0)

  DSTAGE(0, 0);
  asm volatile("s_waitcnt vmcnt(0)" ::: "memory");
  __builtin_amdgcn_s_barrier();
  __builtin_amdgcn_sched_barrier(0);

  const int NT2 = Sc / 128; // 16
  for (int tt = 0; tt < NT2; ++tt) {
    const int cur = tt & 1;
    if (tt + 1 < NT2) DSTAGE(cur ^ 1, (tt + 1) * 128);

    const char* K_ = (const char*)lK[cur];
    const char* VT_ = (const char*)lVT[cur];

#pragma unroll
    for (int s64 = 0; s64 < 2; ++s64) {
#pragma unroll
      for (int sel = 0; sel < 2; ++sel) {
        bf16x4 pa[2][2]; // [sub][ct_i]
        __builtin_amdgcn_s_setprio(1);
#pragma unroll
        for (int ci = 0; ci < 2; ++ci) {
          const int ct = sel * 2 + ci;
          // one kf pair serves BOTH subs (fragment is q-row-independent)
          bf16x8 kf0 = *reinterpret_cast<const bf16x8*>(
              K_ + (((s64 * 64 + ct * 16 + l15) * 128 + lhi * 16) ^ swzK));
          bf16x8 kf1 = *reinterpret_cast<const bf16x8*>(
              K_ + (((s64 * 64 + ct * 16 + l15) * 128 + 64 + lhi * 16) ^ swzK));
#pragma unroll
          for (int s = 0; s < 2; ++s) {
            f32x4 z = {};
            z = __builtin_amdgcn_mfma_f32_16x16x32_bf16(kf0, qf[s][0], z, 0, 0, 0);
            z = __builtin_amdgcn_mfma_f32_16x16x32_bf16(kf1, qf[s][1], z, 0, 0, 0);
#pragma unroll
            for (int jj = 0; jj < 4; ++jj)
              pa[s][ci][jj] = (bf16_t)fexp2(z[jj]);
            lsum[s] = mfma16(pa[s][ci], ones4, lsum[s]);
          }
        }
        __builtin_amdgcn_s_setprio(0);
        // PV: one Vt b128 serves both ct-halves AND both subs
#pragma unroll
        for (int dt = 0; dt < 4; ++dt) {
          bf16x8 vb2 = *reinterpret_cast<const bf16x8*>(
              VT_ + (((dt * 16 + l15) * 256 + s64 * 128 + lhi * 32 + sel * 16) ^ swzK));
          bf16x4 vlo = __builtin_shufflevector(vb2, vb2, 0, 1, 2, 3);
          bf16x4 vhi = __builtin_shufflevector(vb2, vb2, 4, 5, 6, 7);
#pragma unroll
          for (int s = 0; s < 2; ++s) {
            xacc[s][dt] = mfma16(pa[s][0], vlo, xacc[s][dt]);
            xacc[s][dt] = mfma16(pa[s][1], vhi, xacc[s][dt]);
          }
        }
      }
    }

    asm volatile("s_waitcnt vmcnt(0)" ::: "memory");
    __builtin_amdgcn_s_barrier();
    __builtin_amdgcn_sched_barrier(0);
  }
#undef DSTAGE

#pragma unroll
  for (int s = 0; s < 2; ++s) {
    float iO[4];
#pragma unroll
    for (int jj = 0; jj < 4; ++jj) iO[jj] = 1.0f / lsum[s][jj];
    unsigned short* xp =
        X + base + (size_t)(q0 + wv * 32 + s * 16) * Dc + hoff;
#pragma unroll
    for (int dt = 0; dt < 4; ++dt)
#pragma unroll
      for (int jj = 0; jj < 4; ++jj) {
        int r = lhi * 4 + jj;
        xp[(size_t)r * Dc + dt * 16 + l15] = f2bf(xacc[s][dt][jj] * iO[jj]);
      }
  }
}

// ---------------- launch ----------------
extern "C" void kernel_launch(void* const* d_in, const int* in_sizes, int n_in,
                              void* d_out, int out_size, void* d_ws, size_t ws_size,
                              hipStream_t stream) {
  const float* query = (const float*)d_in[0];
  const float* key   = (const float*)d_in[1];
  const float* value = (const float*)d_in[2];
  const float* Wq = (const float*)d_in[3];
  const float* bq = (const float*)d_in[4];
  const float* Wk = (const float*)d_in[5];
  const float* bk = (const float*)d_in[6];
  const float* Wv = (const float*)d_in[7];
  const float* bv = (const float*)d_in[8];
  const float* Wo = (const float*)d_in[9];
  const float* bo = (const float*)d_in[10];

  const size_t NBS = (size_t)Mrows * Dc; // 8388608
  const size_t NW  = (size_t)Dc * Dc;    // 1048576
  unsigned short* bWq  = (unsigned short*)d_ws;
  unsigned short* bWk  = bWq + NW;
  unsigned short* bWv  = bWk + NW;
  unsigned short* bWo  = bWv + NW;
  unsigned short* Qp   = bWo + NW;
  unsigned short* Kp   = Qp + NBS;
  unsigned short* Vtp  = Kp + NBS; // V projection, TRANSPOSED + field-swapped
  unsigned short* Xp   = Vtp + NBS;

  // weights: 4 contiguous segments (bWq..bWo); lg = log2(NW/4) = 18
  // (input fp32->bf16 cvt is fused into the QKV GEMM's A-staging)
  cvt_bf16_seg_kernel<<<(int)(4 * NW / 1024), 256, 0, stream>>>(
      Wq, Wk, Wv, Wo, bWq, 18);

  // fused Q/K/V projections, fp32-A: z selects; Q prescale folds 1/sqrt(DK)
  // AND log2(e) (attn softmax runs in exp2 domain)
  gemm_dbuf_kernel<true><<<dim3(Dc / 128, Mrows / 128, 3), 256, 0, stream>>>(
      query, key, value, bWq, bWk, bWv, bq, bk, bv, Qp, Kp, Vtp,
      Mrows, Dc, Dc, 0.125f * 1.44269504088896340736f);

  attn_kernel<<<dim3(Sc / 256, Hc, Bc), 512, 0, stream>>>(Qp, Kp, Vtp, Xp);

  gemm_dbuf_kernel<false><<<dim3(Dc / 128, Mrows / 128, 1), 256, 0, stream>>>(
      Xp, nullptr, nullptr, bWo, nullptr, nullptr, bo, nullptr, nullptr,
      d_out, nullptr, nullptr, Mrows, Dc, Dc, 1.0f);
}